// Round 9
// baseline (294.450 us; speedup 1.0000x reference)
//
#include <hip/hip_runtime.h>
#include <cstdint>

#define N_NODES 50000
#define N_EDGES 500000
#define ET (N_NODES + N_EDGES)   /* 550000 edges incl. self-loops */
#define EBLK 2149                /* ceil(ET/256) */
#define NEBLK8 1563              /* ne vec8 chunks: 400000 / 256 */

typedef unsigned short u16;
typedef unsigned int   u32;
typedef __attribute__((ext_vector_type(8))) short short8;   // 8 bf16 (4 VGPRs)
typedef __attribute__((ext_vector_type(4))) float f32x4;

__device__ __forceinline__ float bf2f(u16 s) { return __uint_as_float((u32)s << 16); }
__device__ __forceinline__ u16 f2bf(float f) {          // round-to-nearest-even
  u32 u = __float_as_uint(f);
  u32 r = (u + 0x7FFFu + ((u >> 16) & 1u)) >> 16;
  return (u16)r;
}
__device__ __forceinline__ void unpack8(uint4 u, float* f) {  // 8 bf16 -> fp32
  f[0] = __uint_as_float(u.x << 16); f[1] = __uint_as_float(u.x & 0xffff0000u);
  f[2] = __uint_as_float(u.y << 16); f[3] = __uint_as_float(u.y & 0xffff0000u);
  f[4] = __uint_as_float(u.z << 16); f[5] = __uint_as_float(u.z & 0xffff0000u);
  f[6] = __uint_as_float(u.w << 16); f[7] = __uint_as_float(u.w & 0xffff0000u);
}
__device__ __forceinline__ float lrelu(float v) { return v >= 0.f ? v : 0.2f * v; }

// per-wave inline dtype detection (deterministic: same 128 samples every wave)
__device__ __forceinline__ int detect_fp32(const u16* __restrict__ ne) {
  int lane = threadIdx.x & 63;
  int bad = 0;
  #pragma unroll
  for (int j = 0; j < 2; ++j) {
    float v = fabsf(bf2f(ne[lane * 2 + j * 128]));  // even positions only
    bad += (!(v < 16.0f)) ? 1 : 0;                  // catches NaN too
  }
  #pragma unroll
  for (int off = 32; off >= 1; off >>= 1) bad += __shfl_xor(bad, off, 64);
  return bad > 16;                                  // 1 => inputs are fp32
}

// ---------------- k_prep: degree + ne cvt (vec8) + transposes + params ----
__global__ __launch_bounds__(256) void k_prep(const int* __restrict__ ei,
                                              int* __restrict__ deg,
                                              const void* __restrict__ ne_src,
                                              u16* __restrict__ ne_b,
                                              const void* __restrict__ w1src,
                                              u16* __restrict__ W1t,
                                              const void* __restrict__ w2src,
                                              u16* __restrict__ W2t,
                                              const void* s0, const void* s1,
                                              const void* s2, const void* s3,
                                              const void* s4, const void* s5,
                                              float* d0, float* d1, float* d2,
                                              float* d3, float* d4, float* d5) {
  int b = blockIdx.x, tid = threadIdx.x;
  if (b < EBLK) {                                    // degree histogram
    int e = b * 256 + tid;
    if (e < ET) {
      int d = (e < N_EDGES) ? ei[N_EDGES + e] : (e - N_EDGES);
      atomicAdd(&deg[d], 1);
    }
    return;
  }
  int fp32 = detect_fp32((const u16*)ne_src);
  b -= EBLK;
  if (b < NEBLK8) {                                  // ne -> bf16, 8 elems/thread
    int idx = b * 256 + tid;
    if (idx < 400000) {                              // 3.2M / 8
      if (fp32) {
        const float4* f4 = (const float4*)ne_src;
        float4 a = f4[idx * 2], c = f4[idx * 2 + 1];
        uint4 o;
        o.x = (u32)f2bf(a.x) | ((u32)f2bf(a.y) << 16);
        o.y = (u32)f2bf(a.z) | ((u32)f2bf(a.w) << 16);
        o.z = (u32)f2bf(c.x) | ((u32)f2bf(c.y) << 16);
        o.w = (u32)f2bf(c.z) | ((u32)f2bf(c.w) << 16);
        ((uint4*)ne_b)[idx] = o;
      } else {
        ((uint4*)ne_b)[idx] = ((const uint4*)ne_src)[idx];
      }
    }
    return;
  }
  b -= NEBLK8;
  if (b < 640) {                                     // weight transposes
    int i = b * 256 + tid;
    if (i < 32768) {                                 // W1: K=64, N=512
      int n = i >> 6, k = i & 63;
      W1t[i] = fp32 ? f2bf(((const float*)w1src)[k * 512 + n])
                    : ((const u16*)w1src)[k * 512 + n];
    } else {                                         // W2: K=512, N=256
      int j = i - 32768;
      int n = j >> 9, k = j & 511;
      W2t[j] = fp32 ? f2bf(((const float*)w2src)[k * 256 + n])
                    : ((const u16*)w2src)[k * 256 + n];
    }
    return;
  }
  b -= 640;
  {                                                  // small param vectors
    int i = b * 256 + tid;
    const void* s; float* d; int j;
    if      (i < 512)  { s = s0; d = d0; j = i; }
    else if (i < 1024) { s = s1; d = d1; j = i - 512; }
    else if (i < 1536) { s = s2; d = d2; j = i - 1024; }
    else if (i < 1792) { s = s3; d = d3; j = i - 1536; }
    else if (i < 2048) { s = s4; d = d4; j = i - 1792; }
    else if (i < 2304) { s = s5; d = d5; j = i - 2048; }
    else return;
    d[j] = fp32 ? ((const float*)s)[j] : bf2f(((const u16*)s)[j]);
  }
}

// ---------------- va vectors, both layers (reads bf16 transposed weights) ----
__global__ void k_vab(const u16* __restrict__ W1t,
                      const float* __restrict__ as1v, const float* __restrict__ ad1v,
                      float* __restrict__ va_s, float* __restrict__ va_d,
                      const u16* __restrict__ W2t,
                      const float* __restrict__ as2v, const float* __restrict__ ad2v,
                      float* __restrict__ va2_s, float* __restrict__ va2_d) {
  if (blockIdx.x == 0) {
    int t = threadIdx.x;           // h = t>>6, k = t&63
    int h = t >> 6, k = t & 63;
    float s = 0.f, d = 0.f;
    for (int c = 0; c < 128; ++c) {
      float w = bf2f(W1t[(size_t)(h * 128 + c) * 64 + k]);
      s = fmaf(as1v[h * 128 + c], w, s);
      d = fmaf(ad1v[h * 128 + c], w, d);
    }
    va_s[t] = s;
    va_d[t] = d;
  } else {
    int k = (blockIdx.x - 1) * 256 + threadIdx.x;
    if (k >= 512) return;
    float s = 0.f, d = 0.f;
    for (int c = 0; c < 256; ++c) {
      float w = bf2f(W2t[(size_t)c * 512 + k]);
      s = fmaf(as2v[c], w, s);
      d = fmaf(ad2v[c], w, d);
    }
    va2_s[k] = s;
    va2_d[k] = d;
  }
}

// ---------------- CSR scan ----------------
__global__ __launch_bounds__(1024) void k_partial(const int* __restrict__ deg,
                                                  int* __restrict__ excl,
                                                  int* __restrict__ btot) {
  __shared__ int wsum[16];
  int tid = threadIdx.x;
  int i = blockIdx.x * 1024 + tid;
  int v = (i < N_NODES) ? deg[i] : 0;
  int lane = tid & 63, wid = tid >> 6;
  int incl = v;
  #pragma unroll
  for (int off = 1; off < 64; off <<= 1) {
    int t = __shfl_up(incl, off, 64);
    if (lane >= off) incl += t;
  }
  if (lane == 63) wsum[wid] = incl;
  __syncthreads();
  int prefix = 0;
  for (int w = 0; w < wid; ++w) prefix += wsum[w];
  if (i < N_NODES) excl[i] = prefix + incl - v;
  if (tid == 1023) btot[blockIdx.x] = prefix + incl;
}

// k_add with fused block-base scan (replaces k_bases + k_add)
__global__ __launch_bounds__(1024) void k_add(int* __restrict__ row_off,
                                              int* __restrict__ cursor,
                                              const int* __restrict__ btot,
                                              int nb) {
  __shared__ int sbase;
  int tid = threadIdx.x;
  if (tid < 64) {                       // one wave redoes the tiny prefix
    int v = (tid < nb) ? btot[tid] : 0;
    int incl = v;
    #pragma unroll
    for (int off = 1; off < 64; off <<= 1) {
      int t = __shfl_up(incl, off, 64);
      if (tid >= off) incl += t;
    }
    if (tid == (int)blockIdx.x) sbase = incl - v;   // exclusive prefix
  }
  __syncthreads();
  int i = blockIdx.x * 1024 + tid;
  if (i < N_NODES) {
    int r = row_off[i] + sbase;
    row_off[i] = r;
    cursor[i] = r;
  }
  if (blockIdx.x == 0 && tid == 0) row_off[N_NODES] = ET;
}

// ---------------- k_scal: scatter (u16 srcs) + alpha1 (16-wide reductions) ----
__global__ __launch_bounds__(256) void k_scal(const int* __restrict__ ei,
                                              int* __restrict__ cursor,
                                              u16* __restrict__ srcs,
                                              const u16* __restrict__ ne_b,
                                              const float* __restrict__ va_s,
                                              const float* __restrict__ va_d,
                                              float* __restrict__ as_o,
                                              float* __restrict__ ad_o) {
  int b = blockIdx.x;
  if (b < EBLK) {                                    // scatter
    int e = b * 256 + threadIdx.x;
    if (e >= ET) return;
    int s, d;
    if (e < N_EDGES) { s = ei[e]; d = ei[N_EDGES + e]; }
    else { s = d = e - N_EDGES; }
    int pos = atomicAdd(&cursor[d], 1);
    srcs[pos] = (u16)s;                              // node ids < 65536
    return;
  }
  b -= EBLK;                                         // alpha1: wave per node
  int wid = threadIdx.x >> 6, lane = threadIdx.x & 63;
  int n = b * 4 + wid;
  if (n >= N_NODES) return;
  int h = lane >> 4, il = lane & 15;                 // head, lane-in-group
  u32 u2[2];
  *(uint2*)u2 = *(const uint2*)(ne_b + (size_t)n * 64 + il * 4);
  float f[4];
  f[0] = bf2f((u16)u2[0]); f[1] = bf2f((u16)(u2[0] >> 16));
  f[2] = bf2f((u16)u2[1]); f[3] = bf2f((u16)(u2[1] >> 16));
  float4 vs = *(const float4*)(va_s + h * 64 + il * 4);
  float4 vd = *(const float4*)(va_d + h * 64 + il * 4);
  float s = f[0] * vs.x + f[1] * vs.y + f[2] * vs.z + f[3] * vs.w;
  float d = f[0] * vd.x + f[1] * vd.y + f[2] * vd.z + f[3] * vd.w;
  #pragma unroll
  for (int off = 8; off >= 1; off >>= 1) {           // 16-wide reductions
    s += __shfl_xor(s, off, 64);
    d += __shfl_xor(d, off, 64);
  }
  if (il == 0) { as_o[n * 4 + h] = s; ad_o[n * 4 + h] = d; }
}

// ---- pass 1: GEMM + bias + ELU -> alpha2 (as2/ad2), NO x2, head-major A ----
// aggne is head-major [4][N][64]: each block streams a dense 128x128B panel
// (full-line sequential). K=64 fits one LDS tile -> single stage, ONE barrier.
#define ASTR 72    /* 144B row stride: 16B-aligned, 2-way bank alias (free) */
__global__ __launch_bounds__(256) void k_gemm_as2(const u16* __restrict__ aggne,
                                                  const u16* __restrict__ W1t,
                                                  const float* __restrict__ b1f,
                                                  const float* __restrict__ va2_s,
                                                  const float* __restrict__ va2_d,
                                                  float* __restrict__ as2,
                                                  float* __restrict__ ad2, int M) {
  __shared__ __align__(16) u16 As[128 * ASTR];   // 18.4 KB
  __shared__ __align__(16) u16 Bs[128 * ASTR];   // 18.4 KB
  const int tid = threadIdx.x;
  const int lane = tid & 63, wid = tid >> 6;
  const int wr = (wid >> 1) * 64, wc = (wid & 1) * 64;
  const int m = lane & 15, q = lane >> 4;
  const int row0 = blockIdx.x * 128, head = blockIdx.y;
  const u16* Ah = aggne + (size_t)head * N_NODES * 64;
  const u16* Bt = W1t + (size_t)head * 128 * 64;   // [128 cols][64 K]
  #pragma unroll
  for (int i = 0; i < 4; ++i) {               // stage A 128x64 (full K)
    int v = tid + i * 256;                    // 1024 chunks of 8 u16
    int row = v >> 3, ch = (v & 7) * 8;
    uint4 u = make_uint4(0, 0, 0, 0);
    int gr = row0 + row;
    if (gr < M) u = *(const uint4*)(Ah + (size_t)gr * 64 + ch);
    *(uint4*)(As + row * ASTR + ch) = u;
  }
  #pragma unroll
  for (int i = 0; i < 4; ++i) {               // stage B 128x64 (full K)
    int v = tid + i * 256;
    int row = v >> 3, ch = (v & 7) * 8;
    uint4 u = *(const uint4*)(Bt + (size_t)row * 64 + ch);
    *(uint4*)(Bs + row * ASTR + ch) = u;
  }
  __syncthreads();                            // the only barrier
  f32x4 acc[4][4] = {};
  #pragma unroll
  for (int kk = 0; kk < 2; ++kk) {
    short8 af[4], bfr[4];
    #pragma unroll
    for (int t = 0; t < 4; ++t) {
      af[t]  = *(const short8*)(As + (wr + t * 16 + m) * ASTR + kk * 32 + q * 8);
      bfr[t] = *(const short8*)(Bs + (wc + t * 16 + m) * ASTR + kk * 32 + q * 8);
    }
    #pragma unroll
    for (int mt = 0; mt < 4; ++mt)
      #pragma unroll
      for (int nt = 0; nt < 4; ++nt)
        acc[mt][nt] = __builtin_amdgcn_mfma_f32_16x16x32_bf16(
            af[mt], bfr[nt], acc[mt][nt], 0, 0, 0);
  }
  // register epilogue: bias+ELU, alpha2 partial dot, 16-lane reduce, atomics
  float vsr[4], vdr[4], br[4];
  #pragma unroll
  for (int nt = 0; nt < 4; ++nt) {
    int cb = head * 128 + wc + nt * 16 + m;
    br[nt] = b1f[cb]; vsr[nt] = va2_s[cb]; vdr[nt] = va2_d[cb];
  }
  #pragma unroll
  for (int mt = 0; mt < 4; ++mt) {
    float sp[4] = {}, dp[4] = {};
    #pragma unroll
    for (int nt = 0; nt < 4; ++nt)
      #pragma unroll
      for (int r = 0; r < 4; ++r) {
        float v = acc[mt][nt][r] + br[nt];
        v = v > 0.f ? v : (__expf(v) - 1.0f);   // ELU
        sp[r] = fmaf(v, vsr[nt], sp[r]);
        dp[r] = fmaf(v, vdr[nt], dp[r]);
      }
    #pragma unroll
    for (int r = 0; r < 4; ++r) {
      #pragma unroll
      for (int off = 1; off <= 8; off <<= 1) {  // reduce over m-lanes
        sp[r] += __shfl_xor(sp[r], off, 64);
        dp[r] += __shfl_xor(dp[r], off, 64);
      }
      int gr = row0 + wr + mt * 16 + q * 4 + r;
      if (m == 0 && gr < M) {
        atomicAdd(&as2[gr], sp[r]);
        atomicAdd(&ad2[gr], dp[r]);
      }
    }
  }
}

// ---- pass 2: GEMM recompute + bias + ELU + c[n]-weighted colsum (head-major) --
__global__ __launch_bounds__(256) void k_gemm_ws(const u16* __restrict__ aggne,
                                                 const u16* __restrict__ W1t,
                                                 const float* __restrict__ b1f,
                                                 const float* __restrict__ cwt,
                                                 float* __restrict__ s_vec, int M) {
  __shared__ __align__(16) u16 As[128 * ASTR];
  __shared__ __align__(16) u16 Bs[128 * ASTR];
  __shared__ float part[128];
  const int tid = threadIdx.x;
  const int lane = tid & 63, wid = tid >> 6;
  const int wr = (wid >> 1) * 64, wc = (wid & 1) * 64;
  const int m = lane & 15, q = lane >> 4;
  const int row0 = blockIdx.x * 128, head = blockIdx.y;
  const u16* Ah = aggne + (size_t)head * N_NODES * 64;
  const u16* Bt = W1t + (size_t)head * 128 * 64;
  #pragma unroll
  for (int i = 0; i < 4; ++i) {               // stage A 128x64 (full K)
    int v = tid + i * 256;
    int row = v >> 3, ch = (v & 7) * 8;
    uint4 u = make_uint4(0, 0, 0, 0);
    int gr = row0 + row;
    if (gr < M) u = *(const uint4*)(Ah + (size_t)gr * 64 + ch);
    *(uint4*)(As + row * ASTR + ch) = u;
  }
  #pragma unroll
  for (int i = 0; i < 4; ++i) {               // stage B 128x64 (full K)
    int v = tid + i * 256;
    int row = v >> 3, ch = (v & 7) * 8;
    uint4 u = *(const uint4*)(Bt + (size_t)row * 64 + ch);
    *(uint4*)(Bs + row * ASTR + ch) = u;
  }
  if (tid < 128) part[tid] = 0.f;
  __syncthreads();
  f32x4 acc[4][4] = {};
  #pragma unroll
  for (int kk = 0; kk < 2; ++kk) {
    short8 af[4], bfr[4];
    #pragma unroll
    for (int t = 0; t < 4; ++t) {
      af[t]  = *(const short8*)(As + (wr + t * 16 + m) * ASTR + kk * 32 + q * 8);
      bfr[t] = *(const short8*)(Bs + (wc + t * 16 + m) * ASTR + kk * 32 + q * 8);
    }
    #pragma unroll
    for (int mt = 0; mt < 4; ++mt)
      #pragma unroll
      for (int nt = 0; nt < 4; ++nt)
        acc[mt][nt] = __builtin_amdgcn_mfma_f32_16x16x32_bf16(
            af[mt], bfr[nt], acc[mt][nt], 0, 0, 0);
  }
  // per-row weights: coalesced load + shfl broadcast
  float c_l = 0.f;
  int crow = row0 + wr + lane;
  if (crow < M) c_l = cwt[crow];
  float cvr[16];
  #pragma unroll
  for (int mt = 0; mt < 4; ++mt)
    #pragma unroll
    for (int r = 0; r < 4; ++r)
      cvr[mt * 4 + r] = __shfl(c_l, mt * 16 + q * 4 + r, 64);
  float colacc[4] = {};
  #pragma unroll
  for (int nt = 0; nt < 4; ++nt) {
    float b = b1f[head * 128 + wc + nt * 16 + m];
    #pragma unroll
    for (int mt = 0; mt < 4; ++mt)
      #pragma unroll
      for (int r = 0; r < 4; ++r) {
        float v = acc[mt][nt][r] + b;
        v = v > 0.f ? v : (__expf(v) - 1.0f);   // ELU
        colacc[nt] = fmaf(cvr[mt * 4 + r], v, colacc[nt]);
      }
  }
  #pragma unroll
  for (int nt = 0; nt < 4; ++nt) {              // reduce over q-lanes
    colacc[nt] += __shfl_xor(colacc[nt], 16, 64);
    colacc[nt] += __shfl_xor(colacc[nt], 32, 64);
    if (q == 0) atomicAdd(&part[wc + nt * 16 + m], colacc[nt]);
  }
  __syncthreads();
  if (tid < 128) atomicAdd(&s_vec[head * 128 + tid], part[tid]);
}

// ---------------- fused layer-1 aggregation (round-3 form, head-major out) ----
__global__ __launch_bounds__(256) void k_fagg1(const int* __restrict__ row_off,
                                               const u16* __restrict__ srcs,
                                               const u16* __restrict__ ne_b,
                                               const float* __restrict__ as1,
                                               const float* __restrict__ ad1,
                                               u16* __restrict__ aggne) {
  int wid = threadIdx.x >> 6, lane = threadIdx.x & 63;
  int n = blockIdx.x * 4 + wid;
  if (n >= N_NODES) return;
  int start = row_off[n], end = row_off[n + 1];
  int g = lane >> 4, il = lane & 15;     // head group g, lane-in-group
  float adn_g = ad1[n * 4 + g];
  float sum = 0.f;
  for (int e0 = start; e0 < end; e0 += 16) {
    int e = e0 + il;
    if (e < end) sum += __expf(lrelu(as1[(int)srcs[e] * 4 + g] + adn_g));
  }
  #pragma unroll
  for (int off = 8; off >= 1; off >>= 1) sum += __shfl_xor(sum, off, 64);
  float inv = 1.0f / (sum + 1e-16f);
  float i_[4], d_[4];
  #pragma unroll
  for (int h = 0; h < 4; ++h) {
    i_[h] = __shfl(inv, h * 16, 64);
    d_[h] = __shfl(adn_g, h * 16, 64);
  }
  float acc[4] = {};
  for (int e0 = start; e0 < end; e0 += 64) {
    int lim = end - e0; if (lim > 64) lim = 64;
    int es = e0 + lane;
    int sreg = (int)srcs[es < end ? es : end - 1];
    float4 a = *(const float4*)(as1 + sreg * 4);
    float wreg[4];
    wreg[0] = __expf(lrelu(a.x + d_[0])) * i_[0];
    wreg[1] = __expf(lrelu(a.y + d_[1])) * i_[1];
    wreg[2] = __expf(lrelu(a.z + d_[2])) * i_[2];
    wreg[3] = __expf(lrelu(a.w + d_[3])) * i_[3];
    int j = 0;
    for (; j + 3 < lim; j += 4) {           // 4 rows in flight
      int sa = __shfl(sreg, j, 64),     sb = __shfl(sreg, j + 1, 64);
      int sc = __shfl(sreg, j + 2, 64), sd = __shfl(sreg, j + 3, 64);
      float f0 = bf2f(ne_b[(size_t)sa * 64 + lane]);
      float f1 = bf2f(ne_b[(size_t)sb * 64 + lane]);
      float f2 = bf2f(ne_b[(size_t)sc * 64 + lane]);
      float f3 = bf2f(ne_b[(size_t)sd * 64 + lane]);
      #pragma unroll
      for (int h = 0; h < 4; ++h) {
        acc[h] = fmaf(__shfl(wreg[h], j, 64), f0, acc[h]);
        acc[h] = fmaf(__shfl(wreg[h], j + 1, 64), f1, acc[h]);
        acc[h] = fmaf(__shfl(wreg[h], j + 2, 64), f2, acc[h]);
        acc[h] = fmaf(__shfl(wreg[h], j + 3, 64), f3, acc[h]);
      }
    }
    for (; j < lim; ++j) {
      int sa = __shfl(sreg, j, 64);
      float f0 = bf2f(ne_b[(size_t)sa * 64 + lane]);
      #pragma unroll
      for (int h = 0; h < 4; ++h)
        acc[h] = fmaf(__shfl(wreg[h], j, 64), f0, acc[h]);
    }
  }
  #pragma unroll
  for (int h = 0; h < 4; ++h)     // head-major write: [h][n][64]
    aggne[(size_t)h * (N_NODES * 64) + (size_t)n * 64 + lane] = f2bf(acc[h]);
}

// ---------------- layer-2: per-src total softmax weight c[s], no max pass ----
__global__ __launch_bounds__(256) void k_nodew(const int* __restrict__ row_off,
                                               const u16* __restrict__ srcs,
                                               const float* __restrict__ as2,
                                               const float* __restrict__ ad2,
                                               float* __restrict__ c) {
  int wid = threadIdx.x >> 6, lane = threadIdx.x & 63;
  int n = blockIdx.x * 4 + wid;
  if (n >= N_NODES) return;
  int start = row_off[n], end = row_off[n + 1];
  int deg = end - start;
  float adn = ad2[n];
  if (deg <= 64) {
    int e = start + (lane < deg ? lane : 0);
    int s = (int)srcs[e];
    float ex = (lane < deg) ? __expf(lrelu(as2[s] + adn)) : 0.f;
    float sum = ex;
    #pragma unroll
    for (int off = 32; off >= 1; off >>= 1) sum += __shfl_xor(sum, off, 64);
    float w = ex / (sum + 1e-16f);
    if (lane < deg) atomicAdd(&c[s], w);
  } else {
    float sum = 0.f;
    for (int e = start + lane; e < end; e += 64)
      sum += __expf(lrelu(as2[(int)srcs[e]] + adn));
    #pragma unroll
    for (int off = 32; off >= 1; off >>= 1) sum += __shfl_xor(sum, off, 64);
    float inv = 1.0f / (sum + 1e-16f);
    for (int e = start + lane; e < end; e += 64) {
      int s = (int)srcs[e];
      float w = __expf(lrelu(as2[s] + adn)) * inv;
      atomicAdd(&c[s], w);
    }
  }
}

// ---------------- tiny GEMM + final output (merged) ----------------
__global__ __launch_bounds__(256) void k_tinyfinal(const float* __restrict__ s_vec,
                                                   const u16* __restrict__ W2t,
                                                   const float* __restrict__ b2f,
                                                   float* __restrict__ out,
                                                   int out_size) {
  int wid = threadIdx.x >> 6, lane = threadIdx.x & 63;
  int cbase = blockIdx.x * 64 + wid * 16;
  float sv[8];
  #pragma unroll
  for (int j = 0; j < 8; ++j) sv[j] = s_vec[lane * 8 + j];
  for (int i = 0; i < 16; ++i) {
    int cc = cbase + i;
    uint4 u = *(const uint4*)(W2t + (size_t)cc * 512 + lane * 8);
    float f[8];
    unpack8(u, f);
    float p = 0.f;
    #pragma unroll
    for (int j = 0; j < 8; ++j) p = fmaf(sv[j], f[j], p);
    #pragma unroll
    for (int off = 32; off >= 1; off >>= 1) p += __shfl_xor(p, off, 64);
    if (lane == 0) {
      float val = p * (1.0f / (float)N_NODES) + b2f[cc];
      for (int o = cc; o < out_size; o += 256) out[o] = val;
    }
  }
}

// ---------------- launch ----------------
extern "C" void kernel_launch(void* const* d_in, const int* in_sizes, int n_in,
                              void* d_out, int out_size, void* d_ws, size_t ws_size,
                              hipStream_t stream) {
  (void)in_sizes; (void)n_in; (void)ws_size;
  const int* edge_index = (const int*)d_in[0];
  float* out = (float*)d_out;   // reference output dtype is float32

  char* w = (char*)d_ws;
  size_t off = 0;
  auto alloc = [&](size_t bytes) -> void* {
    void* p = w + off;
    off += (bytes + 255) & ~(size_t)255;
    return p;
  };
  u16*   ne_b    = (u16*)  alloc((size_t)N_NODES * 64 * 2);   // 6.4 MB bf16
  u16*   W1t     = (u16*)  alloc(32768 * 2);                  // [512][64]
  u16*   W2t     = (u16*)  alloc(131072 * 2);                 // [256][512]
  float* as1v    = (float*)alloc(512 * 4);
  float* ad1v    = (float*)alloc(512 * 4);
  float* b1f     = (float*)alloc(512 * 4);
  float* as2v    = (float*)alloc(256 * 4);
  float* ad2v    = (float*)alloc(256 * 4);
  float* b2f     = (float*)alloc(256 * 4);
  float* va_s    = (float*)alloc(256 * 4);
  float* va_d    = (float*)alloc(256 * 4);
  float* va2_s   = (float*)alloc(512 * 4);
  float* va2_d   = (float*)alloc(512 * 4);
  u16*   aggne   = (u16*)  alloc((size_t)N_NODES * 256 * 2);  // 25.6 MB head-major
  float* as1     = (float*)alloc((size_t)N_NODES * 4 * 4);
  float* ad1     = (float*)alloc((size_t)N_NODES * 4 * 4);
  // ---- zeroed-every-call region (contiguous, one memset) ----
  size_t z0 = off;
  float* as2     = (float*)alloc((size_t)N_NODES * 4);   // atomic targets
  float* ad2     = (float*)alloc((size_t)N_NODES * 4);
  float* cwt     = (float*)alloc((size_t)N_NODES * 4);
  float* s_vec   = (float*)alloc(512 * 4);
  int*   deg     = (int*)  alloc((size_t)N_NODES * 4);
  size_t z1 = off;
  // -----------------------------------------------------------
  int*   row_off = (int*)  alloc((size_t)(N_NODES + 1) * 4);
  int*   cursor  = (int*)  alloc((size_t)N_NODES * 4);
  u16*   srcs    = (u16*)  alloc((size_t)ET * 2);             // node ids fit u16
  int*   btot    = (int*)  alloc(64 * 4);

  hipMemsetAsync(w + z0, 0, z1 - z0, stream);

  // prep: degree + ne cvt (vec8) + weight transposes + params
  k_prep<<<EBLK + NEBLK8 + 640 + 9, 256, 0, stream>>>(
      edge_index, deg, d_in[2], ne_b, d_in[3], W1t, d_in[7], W2t,
      d_in[4], d_in[5], d_in[6], d_in[8], d_in[9], d_in[10],
      as1v, ad1v, b1f, as2v, ad2v, b2f);
  k_vab<<<3, 256, 0, stream>>>(W1t, as1v, ad1v, va_s, va_d,
                               W2t, as2v, ad2v, va2_s, va2_d);

  // CSR scan (k_bases fused into k_add)
  k_partial<<<49, 1024, 0, stream>>>(deg, row_off, btot);
  k_add    <<<49, 1024, 0, stream>>>(row_off, cursor, btot, 49);

  // scatter (u16 srcs) + alpha1 (merged, 16-wide reductions)
  k_scal<<<EBLK + (N_NODES + 3) / 4, 256, 0, stream>>>(
      edge_index, cursor, srcs, ne_b, va_s, va_d, as1, ad1);

  // layer 1: fused agg over ne (head-major out), then x2-free GEMM passes
  k_fagg1<<<(N_NODES + 3) / 4, 256, 0, stream>>>(row_off, srcs, ne_b, as1, ad1, aggne);
  dim3 gl1((N_NODES + 127) / 128, 4);
  k_gemm_as2<<<gl1, 256, 0, stream>>>(aggne, W1t, b1f, va2_s, va2_d, as2, ad2,
                                      N_NODES);

  // layer 2 (mean-reassociated, x2 recomputed in-register)
  k_nodew<<<(N_NODES + 3) / 4, 256, 0, stream>>>(row_off, srcs, as2, ad2, cwt);
  k_gemm_ws<<<gl1, 256, 0, stream>>>(aggne, W1t, b1f, cwt, s_vec, N_NODES);
  k_tinyfinal<<<4, 256, 0, stream>>>(s_vec, W2t, b2f, out, out_size);
}

// Round 10
// 282.701 us; speedup vs baseline: 1.0416x; 1.0416x over previous
//
#include <hip/hip_runtime.h>
#include <cstdint>

#define N_NODES 50000
#define N_EDGES 500000
#define ET (N_NODES + N_EDGES)   /* 550000 edges incl. self-loops */
#define EBLK 2149                /* ceil(ET/256) */
#define NEBLK8 1563              /* ne vec8 chunks: 400000 / 256 */

typedef unsigned short u16;
typedef unsigned int   u32;
typedef __attribute__((ext_vector_type(8))) short short8;   // 8 bf16 (4 VGPRs)
typedef __attribute__((ext_vector_type(4))) float f32x4;

__device__ __forceinline__ float bf2f(u16 s) { return __uint_as_float((u32)s << 16); }
__device__ __forceinline__ u16 f2bf(float f) {          // round-to-nearest-even
  u32 u = __float_as_uint(f);
  u32 r = (u + 0x7FFFu + ((u >> 16) & 1u)) >> 16;
  return (u16)r;
}
__device__ __forceinline__ void unpack8(uint4 u, float* f) {  // 8 bf16 -> fp32
  f[0] = __uint_as_float(u.x << 16); f[1] = __uint_as_float(u.x & 0xffff0000u);
  f[2] = __uint_as_float(u.y << 16); f[3] = __uint_as_float(u.y & 0xffff0000u);
  f[4] = __uint_as_float(u.z << 16); f[5] = __uint_as_float(u.z & 0xffff0000u);
  f[6] = __uint_as_float(u.w << 16); f[7] = __uint_as_float(u.w & 0xffff0000u);
}
__device__ __forceinline__ float lrelu(float v) { return v >= 0.f ? v : 0.2f * v; }
// uniform-lane broadcasts via readlane (SALU) instead of ds_bpermute (DS pipe)
__device__ __forceinline__ int rli(int v, int l) {
  return __builtin_amdgcn_readlane(v, l);
}
__device__ __forceinline__ float rlf(float v, int l) {
  return __uint_as_float(__builtin_amdgcn_readlane(__float_as_uint(v), l));
}

// per-wave inline dtype detection (deterministic: same 128 samples every wave)
__device__ __forceinline__ int detect_fp32(const u16* __restrict__ ne) {
  int lane = threadIdx.x & 63;
  int bad = 0;
  #pragma unroll
  for (int j = 0; j < 2; ++j) {
    float v = fabsf(bf2f(ne[lane * 2 + j * 128]));  // even positions only
    bad += (!(v < 16.0f)) ? 1 : 0;                  // catches NaN too
  }
  #pragma unroll
  for (int off = 32; off >= 1; off >>= 1) bad += __shfl_xor(bad, off, 64);
  return bad > 16;                                  // 1 => inputs are fp32
}

// ---------------- k_prep: degree + ne cvt (vec8) + transposes + params ----
__global__ __launch_bounds__(256) void k_prep(const int* __restrict__ ei,
                                              int* __restrict__ deg,
                                              const void* __restrict__ ne_src,
                                              u16* __restrict__ ne_b,
                                              const void* __restrict__ w1src,
                                              u16* __restrict__ W1t,
                                              const void* __restrict__ w2src,
                                              u16* __restrict__ W2t,
                                              const void* s0, const void* s1,
                                              const void* s2, const void* s3,
                                              const void* s4, const void* s5,
                                              float* d0, float* d1, float* d2,
                                              float* d3, float* d4, float* d5) {
  int b = blockIdx.x, tid = threadIdx.x;
  if (b < EBLK) {                                    // degree histogram
    int e = b * 256 + tid;
    if (e < ET) {
      int d = (e < N_EDGES) ? ei[N_EDGES + e] : (e - N_EDGES);
      atomicAdd(&deg[d], 1);
    }
    return;
  }
  int fp32 = detect_fp32((const u16*)ne_src);
  b -= EBLK;
  if (b < NEBLK8) {                                  // ne -> bf16, 8 elems/thread
    int idx = b * 256 + tid;
    if (idx < 400000) {                              // 3.2M / 8
      if (fp32) {
        const float4* f4 = (const float4*)ne_src;
        float4 a = f4[idx * 2], c = f4[idx * 2 + 1];
        uint4 o;
        o.x = (u32)f2bf(a.x) | ((u32)f2bf(a.y) << 16);
        o.y = (u32)f2bf(a.z) | ((u32)f2bf(a.w) << 16);
        o.z = (u32)f2bf(c.x) | ((u32)f2bf(c.y) << 16);
        o.w = (u32)f2bf(c.z) | ((u32)f2bf(c.w) << 16);
        ((uint4*)ne_b)[idx] = o;
      } else {
        ((uint4*)ne_b)[idx] = ((const uint4*)ne_src)[idx];
      }
    }
    return;
  }
  b -= NEBLK8;
  if (b < 640) {                                     // weight transposes
    int i = b * 256 + tid;
    if (i < 32768) {                                 // W1: K=64, N=512
      int n = i >> 6, k = i & 63;
      W1t[i] = fp32 ? f2bf(((const float*)w1src)[k * 512 + n])
                    : ((const u16*)w1src)[k * 512 + n];
    } else {                                         // W2: K=512, N=256
      int j = i - 32768;
      int n = j >> 9, k = j & 511;
      W2t[j] = fp32 ? f2bf(((const float*)w2src)[k * 256 + n])
                    : ((const u16*)w2src)[k * 256 + n];
    }
    return;
  }
  b -= 640;
  {                                                  // small param vectors
    int i = b * 256 + tid;
    const void* s; float* d; int j;
    if      (i < 512)  { s = s0; d = d0; j = i; }
    else if (i < 1024) { s = s1; d = d1; j = i - 512; }
    else if (i < 1536) { s = s2; d = d2; j = i - 1024; }
    else if (i < 1792) { s = s3; d = d3; j = i - 1536; }
    else if (i < 2048) { s = s4; d = d4; j = i - 1792; }
    else if (i < 2304) { s = s5; d = d5; j = i - 2048; }
    else return;
    d[j] = fp32 ? ((const float*)s)[j] : bf2f(((const u16*)s)[j]);
  }
}

// ---------------- CSR partial scan + va vectors (merged; both dep on k_prep) --
__global__ __launch_bounds__(1024) void k_partial(const int* __restrict__ deg,
                                                  int* __restrict__ excl,
                                                  int* __restrict__ btot,
                                                  const u16* __restrict__ W1t,
                                                  const float* __restrict__ as1v,
                                                  const float* __restrict__ ad1v,
                                                  float* __restrict__ va_s,
                                                  float* __restrict__ va_d,
                                                  const u16* __restrict__ W2t,
                                                  const float* __restrict__ as2v,
                                                  const float* __restrict__ ad2v,
                                                  float* __restrict__ va2_s,
                                                  float* __restrict__ va2_d) {
  int tid = threadIdx.x;
  if (blockIdx.x >= 49) {               // vab block (threads 0..767 active)
    if (tid < 256) {                    // layer 1: 256 outputs
      int h = tid >> 6, k = tid & 63;
      float s = 0.f, d = 0.f;
      for (int c = 0; c < 128; ++c) {
        float w = bf2f(W1t[(size_t)(h * 128 + c) * 64 + k]);
        s = fmaf(as1v[h * 128 + c], w, s);
        d = fmaf(ad1v[h * 128 + c], w, d);
      }
      va_s[tid] = s;
      va_d[tid] = d;
    } else if (tid < 768) {             // layer 2: 512 outputs
      int k = tid - 256;
      float s = 0.f, d = 0.f;
      for (int c = 0; c < 256; ++c) {
        float w = bf2f(W2t[(size_t)c * 512 + k]);
        s = fmaf(as2v[c], w, s);
        d = fmaf(ad2v[c], w, d);
      }
      va2_s[k] = s;
      va2_d[k] = d;
    }
    return;
  }
  __shared__ int wsum[16];
  int i = blockIdx.x * 1024 + tid;
  int v = (i < N_NODES) ? deg[i] : 0;
  int lane = tid & 63, wid = tid >> 6;
  int incl = v;
  #pragma unroll
  for (int off = 1; off < 64; off <<= 1) {
    int t = __shfl_up(incl, off, 64);
    if (lane >= off) incl += t;
  }
  if (lane == 63) wsum[wid] = incl;
  __syncthreads();
  int prefix = 0;
  for (int w = 0; w < wid; ++w) prefix += wsum[w];
  if (i < N_NODES) excl[i] = prefix + incl - v;
  if (tid == 1023) btot[blockIdx.x] = prefix + incl;
}

// k_add with fused block-base scan (replaces k_bases + k_add)
__global__ __launch_bounds__(1024) void k_add(int* __restrict__ row_off,
                                              int* __restrict__ cursor,
                                              const int* __restrict__ btot,
                                              int nb) {
  __shared__ int sbase;
  int tid = threadIdx.x;
  if (tid < 64) {                       // one wave redoes the tiny prefix
    int v = (tid < nb) ? btot[tid] : 0;
    int incl = v;
    #pragma unroll
    for (int off = 1; off < 64; off <<= 1) {
      int t = __shfl_up(incl, off, 64);
      if (tid >= off) incl += t;
    }
    if (tid == (int)blockIdx.x) sbase = incl - v;   // exclusive prefix
  }
  __syncthreads();
  int i = blockIdx.x * 1024 + tid;
  if (i < N_NODES) {
    int r = row_off[i] + sbase;
    row_off[i] = r;
    cursor[i] = r;
  }
  if (blockIdx.x == 0 && tid == 0) row_off[N_NODES] = ET;
}

// ---------------- k_scal: scatter (u16 srcs) + alpha1 (16-wide reductions) ----
__global__ __launch_bounds__(256) void k_scal(const int* __restrict__ ei,
                                              int* __restrict__ cursor,
                                              u16* __restrict__ srcs,
                                              const u16* __restrict__ ne_b,
                                              const float* __restrict__ va_s,
                                              const float* __restrict__ va_d,
                                              float* __restrict__ as_o,
                                              float* __restrict__ ad_o) {
  int b = blockIdx.x;
  if (b < EBLK) {                                    // scatter
    int e = b * 256 + threadIdx.x;
    if (e >= ET) return;
    int s, d;
    if (e < N_EDGES) { s = ei[e]; d = ei[N_EDGES + e]; }
    else { s = d = e - N_EDGES; }
    int pos = atomicAdd(&cursor[d], 1);
    srcs[pos] = (u16)s;                              // node ids < 65536
    return;
  }
  b -= EBLK;                                         // alpha1: wave per node
  int wid = threadIdx.x >> 6, lane = threadIdx.x & 63;
  int n = b * 4 + wid;
  if (n >= N_NODES) return;
  int h = lane >> 4, il = lane & 15;                 // head, lane-in-group
  u32 u2[2];
  *(uint2*)u2 = *(const uint2*)(ne_b + (size_t)n * 64 + il * 4);
  float f[4];
  f[0] = bf2f((u16)u2[0]); f[1] = bf2f((u16)(u2[0] >> 16));
  f[2] = bf2f((u16)u2[1]); f[3] = bf2f((u16)(u2[1] >> 16));
  float4 vs = *(const float4*)(va_s + h * 64 + il * 4);
  float4 vd = *(const float4*)(va_d + h * 64 + il * 4);
  float s = f[0] * vs.x + f[1] * vs.y + f[2] * vs.z + f[3] * vs.w;
  float d = f[0] * vd.x + f[1] * vd.y + f[2] * vd.z + f[3] * vd.w;
  #pragma unroll
  for (int off = 8; off >= 1; off >>= 1) {           // 16-wide reductions
    s += __shfl_xor(s, off, 64);
    d += __shfl_xor(d, off, 64);
  }
  if (il == 0) { as_o[n * 4 + h] = s; ad_o[n * 4 + h] = d; }
}

// ---------------- pass 1: GEMM + bias + ELU -> alpha2 (as2/ad2), NO x2 ----
#define LSTR 40
__global__ __launch_bounds__(256) void k_gemm_as2(const u16* __restrict__ aggne,
                                                  const u16* __restrict__ W1t,
                                                  const float* __restrict__ b1f,
                                                  const float* __restrict__ va2_s,
                                                  const float* __restrict__ va2_d,
                                                  float* __restrict__ as2,
                                                  float* __restrict__ ad2, int M) {
  __shared__ __align__(16) u16 As[128 * LSTR];
  __shared__ __align__(16) u16 Bs[128 * LSTR];
  const int tid = threadIdx.x;
  const int lane = tid & 63, wid = tid >> 6;
  const int wr = (wid >> 1) * 64, wc = (wid & 1) * 64;
  const int m = lane & 15, q = lane >> 4;
  const int row0 = blockIdx.x * 128, head = blockIdx.y;
  const u16* Bt = W1t + (size_t)head * 128 * 64;   // [128 cols][64 K]
  f32x4 acc[4][4] = {};
  #pragma unroll
  for (int kk = 0; kk < 64; kk += 32) {
    #pragma unroll
    for (int i = 0; i < 2; ++i) {             // stage A 128x32 (lda=256)
      int v = tid + i * 256;
      int row = v >> 2, ch = (v & 3) * 8;
      uint4 u = make_uint4(0, 0, 0, 0);
      int gr = row0 + row;
      if (gr < M) u = *(const uint4*)(aggne + (size_t)gr * 256 + head * 64 + kk + ch);
      *(uint4*)(As + row * LSTR + ch) = u;
    }
    #pragma unroll
    for (int i = 0; i < 2; ++i) {             // stage Bt 128x32 (stride 64)
      int v = tid + i * 256;
      int row = v >> 2, ch = (v & 3) * 8;
      uint4 u = *(const uint4*)(Bt + (size_t)row * 64 + kk + ch);
      *(uint4*)(Bs + row * LSTR + ch) = u;
    }
    __syncthreads();
    short8 af[4], bfr[4];
    #pragma unroll
    for (int t = 0; t < 4; ++t) {
      af[t]  = *(const short8*)(As + (wr + t * 16 + m) * LSTR + q * 8);
      bfr[t] = *(const short8*)(Bs + (wc + t * 16 + m) * LSTR + q * 8);
    }
    #pragma unroll
    for (int mt = 0; mt < 4; ++mt)
      #pragma unroll
      for (int nt = 0; nt < 4; ++nt)
        acc[mt][nt] = __builtin_amdgcn_mfma_f32_16x16x32_bf16(
            af[mt], bfr[nt], acc[mt][nt], 0, 0, 0);
    __syncthreads();
  }
  // register epilogue: bias+ELU, alpha2 partial dot, 16-lane reduce, atomics
  float vsr[4], vdr[4], br[4];
  #pragma unroll
  for (int nt = 0; nt < 4; ++nt) {
    int cb = head * 128 + wc + nt * 16 + m;
    br[nt] = b1f[cb]; vsr[nt] = va2_s[cb]; vdr[nt] = va2_d[cb];
  }
  #pragma unroll
  for (int mt = 0; mt < 4; ++mt) {
    float sp[4] = {}, dp[4] = {};
    #pragma unroll
    for (int nt = 0; nt < 4; ++nt)
      #pragma unroll
      for (int r = 0; r < 4; ++r) {
        float v = acc[mt][nt][r] + br[nt];
        v = v > 0.f ? v : (__expf(v) - 1.0f);   // ELU
        sp[r] = fmaf(v, vsr[nt], sp[r]);
        dp[r] = fmaf(v, vdr[nt], dp[r]);
      }
    #pragma unroll
    for (int r = 0; r < 4; ++r) {
      #pragma unroll
      for (int off = 1; off <= 8; off <<= 1) {  // reduce over m-lanes
        sp[r] += __shfl_xor(sp[r], off, 64);
        dp[r] += __shfl_xor(dp[r], off, 64);
      }
      int gr = row0 + wr + mt * 16 + q * 4 + r;
      if (m == 0 && gr < M) {
        atomicAdd(&as2[gr], sp[r]);
        atomicAdd(&ad2[gr], dp[r]);
      }
    }
  }
}

// ---------------- pass 2: GEMM recompute + bias + ELU + c[n]-weighted colsum ----
__global__ __launch_bounds__(256) void k_gemm_ws(const u16* __restrict__ aggne,
                                                 const u16* __restrict__ W1t,
                                                 const float* __restrict__ b1f,
                                                 const float* __restrict__ cwt,
                                                 float* __restrict__ s_vec, int M) {
  __shared__ __align__(16) u16 As[128 * LSTR];
  __shared__ __align__(16) u16 Bs[128 * LSTR];
  __shared__ float part[128];
  const int tid = threadIdx.x;
  const int lane = tid & 63, wid = tid >> 6;
  const int wr = (wid >> 1) * 64, wc = (wid & 1) * 64;
  const int m = lane & 15, q = lane >> 4;
  const int row0 = blockIdx.x * 128, head = blockIdx.y;
  const u16* Bt = W1t + (size_t)head * 128 * 64;
  f32x4 acc[4][4] = {};
  #pragma unroll
  for (int kk = 0; kk < 64; kk += 32) {
    #pragma unroll
    for (int i = 0; i < 2; ++i) {
      int v = tid + i * 256;
      int row = v >> 2, ch = (v & 3) * 8;
      uint4 u = make_uint4(0, 0, 0, 0);
      int gr = row0 + row;
      if (gr < M) u = *(const uint4*)(aggne + (size_t)gr * 256 + head * 64 + kk + ch);
      *(uint4*)(As + row * LSTR + ch) = u;
    }
    #pragma unroll
    for (int i = 0; i < 2; ++i) {
      int v = tid + i * 256;
      int row = v >> 2, ch = (v & 3) * 8;
      uint4 u = *(const uint4*)(Bt + (size_t)row * 64 + kk + ch);
      *(uint4*)(Bs + row * LSTR + ch) = u;
    }
    __syncthreads();
    short8 af[4], bfr[4];
    #pragma unroll
    for (int t = 0; t < 4; ++t) {
      af[t]  = *(const short8*)(As + (wr + t * 16 + m) * LSTR + q * 8);
      bfr[t] = *(const short8*)(Bs + (wc + t * 16 + m) * LSTR + q * 8);
    }
    #pragma unroll
    for (int mt = 0; mt < 4; ++mt)
      #pragma unroll
      for (int nt = 0; nt < 4; ++nt)
        acc[mt][nt] = __builtin_amdgcn_mfma_f32_16x16x32_bf16(
            af[mt], bfr[nt], acc[mt][nt], 0, 0, 0);
    __syncthreads();
  }
  if (tid < 128) part[tid] = 0.f;
  // per-row weights: coalesced load + shfl broadcast
  float c_l = 0.f;
  int crow = row0 + wr + lane;
  if (crow < M) c_l = cwt[crow];
  float cvr[16];
  #pragma unroll
  for (int mt = 0; mt < 4; ++mt)
    #pragma unroll
    for (int r = 0; r < 4; ++r)
      cvr[mt * 4 + r] = rlf(c_l, mt * 16 + q * 4 + r);
  __syncthreads();
  float colacc[4] = {};
  #pragma unroll
  for (int nt = 0; nt < 4; ++nt) {
    float b = b1f[head * 128 + wc + nt * 16 + m];
    #pragma unroll
    for (int mt = 0; mt < 4; ++mt)
      #pragma unroll
      for (int r = 0; r < 4; ++r) {
        float v = acc[mt][nt][r] + b;
        v = v > 0.f ? v : (__expf(v) - 1.0f);   // ELU
        colacc[nt] = fmaf(cvr[mt * 4 + r], v, colacc[nt]);
      }
  }
  #pragma unroll
  for (int nt = 0; nt < 4; ++nt) {              // reduce over q-lanes
    colacc[nt] += __shfl_xor(colacc[nt], 16, 64);
    colacc[nt] += __shfl_xor(colacc[nt], 32, 64);
    if (q == 0) atomicAdd(&part[wc + nt * 16 + m], colacc[nt]);
  }
  __syncthreads();
  if (tid < 128) atomicAdd(&s_vec[head * 128 + tid], part[tid]);
}

// ---------------- fused layer-1 aggregation (round-3 form + readlane bcast) ----
__global__ __launch_bounds__(256) void k_fagg1(const int* __restrict__ row_off,
                                               const u16* __restrict__ srcs,
                                               const u16* __restrict__ ne_b,
                                               const float* __restrict__ as1,
                                               const float* __restrict__ ad1,
                                               u16* __restrict__ aggne) {
  int wid = threadIdx.x >> 6, lane = threadIdx.x & 63;
  int n = blockIdx.x * 4 + wid;
  if (n >= N_NODES) return;
  int start = row_off[n], end = row_off[n + 1];
  int g = lane >> 4, il = lane & 15;     // head group g, lane-in-group
  float adn_g = ad1[n * 4 + g];
  float sum = 0.f;
  for (int e0 = start; e0 < end; e0 += 16) {
    int e = e0 + il;
    if (e < end) sum += __expf(lrelu(as1[(int)srcs[e] * 4 + g] + adn_g));
  }
  #pragma unroll
  for (int off = 8; off >= 1; off >>= 1) sum += __shfl_xor(sum, off, 64);
  float inv = 1.0f / (sum + 1e-16f);
  float i_[4], d_[4];
  #pragma unroll
  for (int h = 0; h < 4; ++h) {
    i_[h] = rlf(inv, h * 16);
    d_[h] = rlf(adn_g, h * 16);
  }
  float acc[4] = {};
  for (int e0 = start; e0 < end; e0 += 64) {
    int lim = end - e0; if (lim > 64) lim = 64;
    int es = e0 + lane;
    int sreg = (int)srcs[es < end ? es : end - 1];
    float4 a = *(const float4*)(as1 + sreg * 4);
    float wreg[4];
    wreg[0] = __expf(lrelu(a.x + d_[0])) * i_[0];
    wreg[1] = __expf(lrelu(a.y + d_[1])) * i_[1];
    wreg[2] = __expf(lrelu(a.z + d_[2])) * i_[2];
    wreg[3] = __expf(lrelu(a.w + d_[3])) * i_[3];
    int j = 0;
    for (; j + 3 < lim; j += 4) {           // 4 rows in flight, SALU broadcasts
      int sa = rli(sreg, j),     sb = rli(sreg, j + 1);
      int sc = rli(sreg, j + 2), sd = rli(sreg, j + 3);
      float f0 = bf2f(ne_b[(size_t)sa * 64 + lane]);
      float f1 = bf2f(ne_b[(size_t)sb * 64 + lane]);
      float f2 = bf2f(ne_b[(size_t)sc * 64 + lane]);
      float f3 = bf2f(ne_b[(size_t)sd * 64 + lane]);
      #pragma unroll
      for (int h = 0; h < 4; ++h) {
        acc[h] = fmaf(rlf(wreg[h], j), f0, acc[h]);
        acc[h] = fmaf(rlf(wreg[h], j + 1), f1, acc[h]);
        acc[h] = fmaf(rlf(wreg[h], j + 2), f2, acc[h]);
        acc[h] = fmaf(rlf(wreg[h], j + 3), f3, acc[h]);
      }
    }
    for (; j < lim; ++j) {
      int sa = rli(sreg, j);
      float f0 = bf2f(ne_b[(size_t)sa * 64 + lane]);
      #pragma unroll
      for (int h = 0; h < 4; ++h)
        acc[h] = fmaf(rlf(wreg[h], j), f0, acc[h]);
    }
  }
  #pragma unroll
  for (int h = 0; h < 4; ++h)
    aggne[(size_t)n * 256 + h * 64 + lane] = f2bf(acc[h]);
}

// ---------------- layer-2: per-src total softmax weight c[s], no max pass ----
__global__ __launch_bounds__(256) void k_nodew(const int* __restrict__ row_off,
                                               const u16* __restrict__ srcs,
                                               const float* __restrict__ as2,
                                               const float* __restrict__ ad2,
                                               float* __restrict__ c) {
  int wid = threadIdx.x >> 6, lane = threadIdx.x & 63;
  int n = blockIdx.x * 4 + wid;
  if (n >= N_NODES) return;
  int start = row_off[n], end = row_off[n + 1];
  int deg = end - start;
  float adn = ad2[n];
  if (deg <= 64) {
    int e = start + (lane < deg ? lane : 0);
    int s = (int)srcs[e];
    float ex = (lane < deg) ? __expf(lrelu(as2[s] + adn)) : 0.f;
    float sum = ex;
    #pragma unroll
    for (int off = 32; off >= 1; off >>= 1) sum += __shfl_xor(sum, off, 64);
    float w = ex / (sum + 1e-16f);
    if (lane < deg) atomicAdd(&c[s], w);
  } else {
    float sum = 0.f;
    for (int e = start + lane; e < end; e += 64)
      sum += __expf(lrelu(as2[(int)srcs[e]] + adn));
    #pragma unroll
    for (int off = 32; off >= 1; off >>= 1) sum += __shfl_xor(sum, off, 64);
    float inv = 1.0f / (sum + 1e-16f);
    for (int e = start + lane; e < end; e += 64) {
      int s = (int)srcs[e];
      float w = __expf(lrelu(as2[s] + adn)) * inv;
      atomicAdd(&c[s], w);
    }
  }
}

// ---------------- tiny GEMM + final output (merged) ----------------
__global__ __launch_bounds__(256) void k_tinyfinal(const float* __restrict__ s_vec,
                                                   const u16* __restrict__ W2t,
                                                   const float* __restrict__ b2f,
                                                   float* __restrict__ out,
                                                   int out_size) {
  int wid = threadIdx.x >> 6, lane = threadIdx.x & 63;
  int cbase = blockIdx.x * 64 + wid * 16;
  float sv[8];
  #pragma unroll
  for (int j = 0; j < 8; ++j) sv[j] = s_vec[lane * 8 + j];
  for (int i = 0; i < 16; ++i) {
    int cc = cbase + i;
    uint4 u = *(const uint4*)(W2t + (size_t)cc * 512 + lane * 8);
    float f[8];
    unpack8(u, f);
    float p = 0.f;
    #pragma unroll
    for (int j = 0; j < 8; ++j) p = fmaf(sv[j], f[j], p);
    #pragma unroll
    for (int off = 32; off >= 1; off >>= 1) p += __shfl_xor(p, off, 64);
    if (lane == 0) {
      float val = p * (1.0f / (float)N_NODES) + b2f[cc];
      for (int o = cc; o < out_size; o += 256) out[o] = val;
    }
  }
}

// ---------------- launch ----------------
extern "C" void kernel_launch(void* const* d_in, const int* in_sizes, int n_in,
                              void* d_out, int out_size, void* d_ws, size_t ws_size,
                              hipStream_t stream) {
  (void)in_sizes; (void)n_in; (void)ws_size;
  const int* edge_index = (const int*)d_in[0];
  float* out = (float*)d_out;   // reference output dtype is float32

  char* w = (char*)d_ws;
  size_t off = 0;
  auto alloc = [&](size_t bytes) -> void* {
    void* p = w + off;
    off += (bytes + 255) & ~(size_t)255;
    return p;
  };
  u16*   ne_b    = (u16*)  alloc((size_t)N_NODES * 64 * 2);   // 6.4 MB bf16
  u16*   W1t     = (u16*)  alloc(32768 * 2);                  // [512][64]
  u16*   W2t     = (u16*)  alloc(131072 * 2);                 // [256][512]
  float* as1v    = (float*)alloc(512 * 4);
  float* ad1v    = (float*)alloc(512 * 4);
  float* b1f     = (float*)alloc(512 * 4);
  float* as2v    = (float*)alloc(256 * 4);
  float* ad2v    = (float*)alloc(256 * 4);
  float* b2f     = (float*)alloc(256 * 4);
  float* va_s    = (float*)alloc(256 * 4);
  float* va_d    = (float*)alloc(256 * 4);
  float* va2_s   = (float*)alloc(512 * 4);
  float* va2_d   = (float*)alloc(512 * 4);
  u16*   aggne   = (u16*)  alloc((size_t)N_NODES * 256 * 2);  // 25.6 MB
  float* as1     = (float*)alloc((size_t)N_NODES * 4 * 4);
  float* ad1     = (float*)alloc((size_t)N_NODES * 4 * 4);
  // ---- zeroed-every-call region (contiguous, one memset) ----
  size_t z0 = off;
  float* as2     = (float*)alloc((size_t)N_NODES * 4);   // atomic targets
  float* ad2     = (float*)alloc((size_t)N_NODES * 4);
  float* cwt     = (float*)alloc((size_t)N_NODES * 4);
  float* s_vec   = (float*)alloc(512 * 4);
  int*   deg     = (int*)  alloc((size_t)N_NODES * 4);
  size_t z1 = off;
  // -----------------------------------------------------------
  int*   row_off = (int*)  alloc((size_t)(N_NODES + 1) * 4);
  int*   cursor  = (int*)  alloc((size_t)N_NODES * 4);
  u16*   srcs    = (u16*)  alloc((size_t)ET * 2);             // node ids fit u16
  int*   btot    = (int*)  alloc(64 * 4);

  hipMemsetAsync(w + z0, 0, z1 - z0, stream);

  // prep: degree + ne cvt (vec8) + weight transposes + params
  k_prep<<<EBLK + NEBLK8 + 640 + 9, 256, 0, stream>>>(
      edge_index, deg, d_in[2], ne_b, d_in[3], W1t, d_in[7], W2t,
      d_in[4], d_in[5], d_in[6], d_in[8], d_in[9], d_in[10],
      as1v, ad1v, b1f, as2v, ad2v, b2f);

  // CSR partial scan + va vectors (merged), then fused add
  k_partial<<<50, 1024, 0, stream>>>(deg, row_off, btot,
                                     W1t, as1v, ad1v, va_s, va_d,
                                     W2t, as2v, ad2v, va2_s, va2_d);
  k_add<<<49, 1024, 0, stream>>>(row_off, cursor, btot, 49);

  // scatter (u16 srcs) + alpha1 (merged, 16-wide reductions)
  k_scal<<<EBLK + (N_NODES + 3) / 4, 256, 0, stream>>>(
      edge_index, cursor, srcs, ne_b, va_s, va_d, as1, ad1);

  // layer 1: fused agg over ne, then x2-free GEMM passes
  k_fagg1<<<(N_NODES + 3) / 4, 256, 0, stream>>>(row_off, srcs, ne_b, as1, ad1, aggne);
  dim3 gl1((N_NODES + 127) / 128, 4);
  k_gemm_as2<<<gl1, 256, 0, stream>>>(aggne, W1t, b1f, va2_s, va2_d, as2, ad2,
                                      N_NODES);

  // layer 2 (mean-reassociated, x2 recomputed in-register)
  k_nodew<<<(N_NODES + 3) / 4, 256, 0, stream>>>(row_off, srcs, as2, ad2, cwt);
  k_gemm_ws<<<gl1, 256, 0, stream>>>(aggne, W1t, b1f, cwt, s_vec, N_NODES);
  k_tinyfinal<<<4, 256, 0, stream>>>(s_vec, W2t, b2f, out, out_size);
}

// Round 11
// 263.786 us; speedup vs baseline: 1.1162x; 1.0717x over previous
//
#include <hip/hip_runtime.h>
#include <cstdint>

#define N_NODES 50000
#define N_EDGES 500000
#define ET (N_NODES + N_EDGES)   /* 550000 edges incl. self-loops */
#define EBLK 2149                /* ceil(ET/256) */
#define NEBLK8 1563              /* ne vec8 chunks: 400000 / 256 */

typedef unsigned short u16;
typedef unsigned int   u32;
typedef __attribute__((ext_vector_type(8))) short short8;   // 8 bf16 (4 VGPRs)
typedef __attribute__((ext_vector_type(4))) float f32x4;

__device__ __forceinline__ float bf2f(u16 s) { return __uint_as_float((u32)s << 16); }
__device__ __forceinline__ u16 f2bf(float f) {          // round-to-nearest-even
  u32 u = __float_as_uint(f);
  u32 r = (u + 0x7FFFu + ((u >> 16) & 1u)) >> 16;
  return (u16)r;
}
__device__ __forceinline__ void unpack8(uint4 u, float* f) {  // 8 bf16 -> fp32
  f[0] = __uint_as_float(u.x << 16); f[1] = __uint_as_float(u.x & 0xffff0000u);
  f[2] = __uint_as_float(u.y << 16); f[3] = __uint_as_float(u.y & 0xffff0000u);
  f[4] = __uint_as_float(u.z << 16); f[5] = __uint_as_float(u.z & 0xffff0000u);
  f[6] = __uint_as_float(u.w << 16); f[7] = __uint_as_float(u.w & 0xffff0000u);
}
__device__ __forceinline__ float lrelu(float v) { return v >= 0.f ? v : 0.2f * v; }
// uniform-lane broadcasts via readlane (SALU) instead of ds_bpermute (DS pipe)
__device__ __forceinline__ int rli(int v, int l) {
  return __builtin_amdgcn_readlane(v, l);
}
__device__ __forceinline__ float rlf(float v, int l) {
  return __uint_as_float(__builtin_amdgcn_readlane(__float_as_uint(v), l));
}

// per-wave inline dtype detection (deterministic: same 128 samples every wave)
__device__ __forceinline__ int detect_fp32(const u16* __restrict__ ne) {
  int lane = threadIdx.x & 63;
  int bad = 0;
  #pragma unroll
  for (int j = 0; j < 2; ++j) {
    float v = fabsf(bf2f(ne[lane * 2 + j * 128]));  // even positions only
    bad += (!(v < 16.0f)) ? 1 : 0;                  // catches NaN too
  }
  #pragma unroll
  for (int off = 32; off >= 1; off >>= 1) bad += __shfl_xor(bad, off, 64);
  return bad > 16;                                  // 1 => inputs are fp32
}

// ---------------- k_prep: degree(+rank) + ne cvt (vec8) + transposes + params --
__global__ __launch_bounds__(256) void k_prep(const int* __restrict__ ei,
                                              int* __restrict__ deg,
                                              u16* __restrict__ relbuf,
                                              const void* __restrict__ ne_src,
                                              u16* __restrict__ ne_b,
                                              const void* __restrict__ w1src,
                                              u16* __restrict__ W1t,
                                              const void* __restrict__ w2src,
                                              u16* __restrict__ W2t,
                                              const void* s0, const void* s1,
                                              const void* s2, const void* s3,
                                              const void* s4, const void* s5,
                                              float* d0, float* d1, float* d2,
                                              float* d3, float* d4, float* d5) {
  int b = blockIdx.x, tid = threadIdx.x;
  if (b < EBLK) {                      // degree histogram + per-edge rank
    int e = b * 256 + tid;
    if (e < ET) {
      int d = (e < N_EDGES) ? ei[N_EDGES + e] : (e - N_EDGES);
      int rel = atomicAdd(&deg[d], 1);
      relbuf[e] = (u16)rel;            // rank within destination segment
    }
    return;
  }
  int fp32 = detect_fp32((const u16*)ne_src);
  b -= EBLK;
  if (b < NEBLK8) {                                  // ne -> bf16, 8 elems/thread
    int idx = b * 256 + tid;
    if (idx < 400000) {                              // 3.2M / 8
      if (fp32) {
        const float4* f4 = (const float4*)ne_src;
        float4 a = f4[idx * 2], c = f4[idx * 2 + 1];
        uint4 o;
        o.x = (u32)f2bf(a.x) | ((u32)f2bf(a.y) << 16);
        o.y = (u32)f2bf(a.z) | ((u32)f2bf(a.w) << 16);
        o.z = (u32)f2bf(c.x) | ((u32)f2bf(c.y) << 16);
        o.w = (u32)f2bf(c.z) | ((u32)f2bf(c.w) << 16);
        ((uint4*)ne_b)[idx] = o;
      } else {
        ((uint4*)ne_b)[idx] = ((const uint4*)ne_src)[idx];
      }
    }
    return;
  }
  b -= NEBLK8;
  if (b < 640) {                                     // weight transposes
    int i = b * 256 + tid;
    if (i < 32768) {                                 // W1: K=64, N=512
      int n = i >> 6, k = i & 63;
      W1t[i] = fp32 ? f2bf(((const float*)w1src)[k * 512 + n])
                    : ((const u16*)w1src)[k * 512 + n];
    } else {                                         // W2: K=512, N=256
      int j = i - 32768;
      int n = j >> 9, k = j & 511;
      W2t[j] = fp32 ? f2bf(((const float*)w2src)[k * 256 + n])
                    : ((const u16*)w2src)[k * 256 + n];
    }
    return;
  }
  b -= 640;
  {                                                  // small param vectors
    int i = b * 256 + tid;
    const void* s; float* d; int j;
    if      (i < 512)  { s = s0; d = d0; j = i; }
    else if (i < 1024) { s = s1; d = d1; j = i - 512; }
    else if (i < 1536) { s = s2; d = d2; j = i - 1024; }
    else if (i < 1792) { s = s3; d = d3; j = i - 1536; }
    else if (i < 2048) { s = s4; d = d4; j = i - 1792; }
    else if (i < 2304) { s = s5; d = d5; j = i - 2048; }
    else return;
    d[j] = fp32 ? ((const float*)s)[j] : bf2f(((const u16*)s)[j]);
  }
}

// ---------------- CSR partial scan + va vectors (merged; both dep on k_prep) --
__global__ __launch_bounds__(1024) void k_partial(const int* __restrict__ deg,
                                                  int* __restrict__ excl,
                                                  int* __restrict__ btot,
                                                  const u16* __restrict__ W1t,
                                                  const float* __restrict__ as1v,
                                                  const float* __restrict__ ad1v,
                                                  float* __restrict__ va_s,
                                                  float* __restrict__ va_d,
                                                  const u16* __restrict__ W2t,
                                                  const float* __restrict__ as2v,
                                                  const float* __restrict__ ad2v,
                                                  float* __restrict__ va2_s,
                                                  float* __restrict__ va2_d) {
  int tid = threadIdx.x;
  if (blockIdx.x >= 49) {               // vab block (threads 0..767 active)
    if (tid < 256) {                    // layer 1: 256 outputs
      int h = tid >> 6, k = tid & 63;
      float s = 0.f, d = 0.f;
      for (int c = 0; c < 128; ++c) {
        float w = bf2f(W1t[(size_t)(h * 128 + c) * 64 + k]);
        s = fmaf(as1v[h * 128 + c], w, s);
        d = fmaf(ad1v[h * 128 + c], w, d);
      }
      va_s[tid] = s;
      va_d[tid] = d;
    } else if (tid < 768) {             // layer 2: 512 outputs
      int k = tid - 256;
      float s = 0.f, d = 0.f;
      for (int c = 0; c < 256; ++c) {
        float w = bf2f(W2t[(size_t)c * 512 + k]);
        s = fmaf(as2v[c], w, s);
        d = fmaf(ad2v[c], w, d);
      }
      va2_s[k] = s;
      va2_d[k] = d;
    }
    return;
  }
  __shared__ int wsum[16];
  int i = blockIdx.x * 1024 + tid;
  int v = (i < N_NODES) ? deg[i] : 0;
  int lane = tid & 63, wid = tid >> 6;
  int incl = v;
  #pragma unroll
  for (int off = 1; off < 64; off <<= 1) {
    int t = __shfl_up(incl, off, 64);
    if (lane >= off) incl += t;
  }
  if (lane == 63) wsum[wid] = incl;
  __syncthreads();
  int prefix = 0;
  for (int w = 0; w < wid; ++w) prefix += wsum[w];
  if (i < N_NODES) excl[i] = prefix + incl - v;
  if (tid == 1023) btot[blockIdx.x] = prefix + incl;
}

// k_add with fused block-base scan (no cursor: scatter uses rank buffer)
__global__ __launch_bounds__(1024) void k_add(int* __restrict__ row_off,
                                              const int* __restrict__ btot,
                                              int nb) {
  __shared__ int sbase;
  int tid = threadIdx.x;
  if (tid < 64) {                       // one wave redoes the tiny prefix
    int v = (tid < nb) ? btot[tid] : 0;
    int incl = v;
    #pragma unroll
    for (int off = 1; off < 64; off <<= 1) {
      int t = __shfl_up(incl, off, 64);
      if (tid >= off) incl += t;
    }
    if (tid == (int)blockIdx.x) sbase = incl - v;   // exclusive prefix
  }
  __syncthreads();
  int i = blockIdx.x * 1024 + tid;
  if (i < N_NODES) row_off[i] += sbase;
  if (blockIdx.x == 0 && tid == 0) row_off[N_NODES] = ET;
}

// ---------------- k_scal: scatter (rank-based, NO atomics) + alpha1 ----------
__global__ __launch_bounds__(256) void k_scal(const int* __restrict__ ei,
                                              const int* __restrict__ row_off,
                                              const u16* __restrict__ relbuf,
                                              u16* __restrict__ srcs,
                                              const u16* __restrict__ ne_b,
                                              const float* __restrict__ va_s,
                                              const float* __restrict__ va_d,
                                              float* __restrict__ as_o,
                                              float* __restrict__ ad_o) {
  int b = blockIdx.x;
  if (b < EBLK) {                                    // scatter: load + store only
    int e = b * 256 + threadIdx.x;
    if (e >= ET) return;
    int s, d;
    if (e < N_EDGES) { s = ei[e]; d = ei[N_EDGES + e]; }
    else { s = d = e - N_EDGES; }
    int pos = row_off[d] + (int)relbuf[e];
    srcs[pos] = (u16)s;                              // node ids < 65536
    return;
  }
  b -= EBLK;                                         // alpha1: wave per node
  int wid = threadIdx.x >> 6, lane = threadIdx.x & 63;
  int n = b * 4 + wid;
  if (n >= N_NODES) return;
  int h = lane >> 4, il = lane & 15;                 // head, lane-in-group
  u32 u2[2];
  *(uint2*)u2 = *(const uint2*)(ne_b + (size_t)n * 64 + il * 4);
  float f[4];
  f[0] = bf2f((u16)u2[0]); f[1] = bf2f((u16)(u2[0] >> 16));
  f[2] = bf2f((u16)u2[1]); f[3] = bf2f((u16)(u2[1] >> 16));
  float4 vs = *(const float4*)(va_s + h * 64 + il * 4);
  float4 vd = *(const float4*)(va_d + h * 64 + il * 4);
  float s = f[0] * vs.x + f[1] * vs.y + f[2] * vs.z + f[3] * vs.w;
  float d = f[0] * vd.x + f[1] * vd.y + f[2] * vd.z + f[3] * vd.w;
  #pragma unroll
  for (int off = 8; off >= 1; off >>= 1) {           // 16-wide reductions
    s += __shfl_xor(s, off, 64);
    d += __shfl_xor(d, off, 64);
  }
  if (il == 0) { as_o[n * 4 + h] = s; ad_o[n * 4 + h] = d; }
}

// ---------------- pass 1: GEMM + bias + ELU -> alpha2 (as2/ad2), NO x2 ----
#define LSTR 40
__global__ __launch_bounds__(256) void k_gemm_as2(const u16* __restrict__ aggne,
                                                  const u16* __restrict__ W1t,
                                                  const float* __restrict__ b1f,
                                                  const float* __restrict__ va2_s,
                                                  const float* __restrict__ va2_d,
                                                  float* __restrict__ as2,
                                                  float* __restrict__ ad2, int M) {
  __shared__ __align__(16) u16 As[128 * LSTR];
  __shared__ __align__(16) u16 Bs[128 * LSTR];
  const int tid = threadIdx.x;
  const int lane = tid & 63, wid = tid >> 6;
  const int wr = (wid >> 1) * 64, wc = (wid & 1) * 64;
  const int m = lane & 15, q = lane >> 4;
  const int row0 = blockIdx.x * 128, head = blockIdx.y;
  const u16* Bt = W1t + (size_t)head * 128 * 64;   // [128 cols][64 K]
  f32x4 acc[4][4] = {};
  #pragma unroll
  for (int kk = 0; kk < 64; kk += 32) {
    #pragma unroll
    for (int i = 0; i < 2; ++i) {             // stage A 128x32 (lda=256)
      int v = tid + i * 256;
      int row = v >> 2, ch = (v & 3) * 8;
      uint4 u = make_uint4(0, 0, 0, 0);
      int gr = row0 + row;
      if (gr < M) u = *(const uint4*)(aggne + (size_t)gr * 256 + head * 64 + kk + ch);
      *(uint4*)(As + row * LSTR + ch) = u;
    }
    #pragma unroll
    for (int i = 0; i < 2; ++i) {             // stage Bt 128x32 (stride 64)
      int v = tid + i * 256;
      int row = v >> 2, ch = (v & 3) * 8;
      uint4 u = *(const uint4*)(Bt + (size_t)row * 64 + kk + ch);
      *(uint4*)(Bs + row * LSTR + ch) = u;
    }
    __syncthreads();
    short8 af[4], bfr[4];
    #pragma unroll
    for (int t = 0; t < 4; ++t) {
      af[t]  = *(const short8*)(As + (wr + t * 16 + m) * LSTR + q * 8);
      bfr[t] = *(const short8*)(Bs + (wc + t * 16 + m) * LSTR + q * 8);
    }
    #pragma unroll
    for (int mt = 0; mt < 4; ++mt)
      #pragma unroll
      for (int nt = 0; nt < 4; ++nt)
        acc[mt][nt] = __builtin_amdgcn_mfma_f32_16x16x32_bf16(
            af[mt], bfr[nt], acc[mt][nt], 0, 0, 0);
    __syncthreads();
  }
  // register epilogue: bias+ELU, alpha2 partial dot, 16-lane reduce, atomics
  float vsr[4], vdr[4], br[4];
  #pragma unroll
  for (int nt = 0; nt < 4; ++nt) {
    int cb = head * 128 + wc + nt * 16 + m;
    br[nt] = b1f[cb]; vsr[nt] = va2_s[cb]; vdr[nt] = va2_d[cb];
  }
  #pragma unroll
  for (int mt = 0; mt < 4; ++mt) {
    float sp[4] = {}, dp[4] = {};
    #pragma unroll
    for (int nt = 0; nt < 4; ++nt)
      #pragma unroll
      for (int r = 0; r < 4; ++r) {
        float v = acc[mt][nt][r] + br[nt];
        v = v > 0.f ? v : (__expf(v) - 1.0f);   // ELU
        sp[r] = fmaf(v, vsr[nt], sp[r]);
        dp[r] = fmaf(v, vdr[nt], dp[r]);
      }
    #pragma unroll
    for (int r = 0; r < 4; ++r) {
      #pragma unroll
      for (int off = 1; off <= 8; off <<= 1) {  // reduce over m-lanes
        sp[r] += __shfl_xor(sp[r], off, 64);
        dp[r] += __shfl_xor(dp[r], off, 64);
      }
      int gr = row0 + wr + mt * 16 + q * 4 + r;
      if (m == 0 && gr < M) {
        atomicAdd(&as2[gr], sp[r]);
        atomicAdd(&ad2[gr], dp[r]);
      }
    }
  }
}

// ---------------- pass 2: GEMM recompute + bias + ELU + c[n]-weighted colsum ----
__global__ __launch_bounds__(256) void k_gemm_ws(const u16* __restrict__ aggne,
                                                 const u16* __restrict__ W1t,
                                                 const float* __restrict__ b1f,
                                                 const float* __restrict__ cwt,
                                                 float* __restrict__ s_vec, int M) {
  __shared__ __align__(16) u16 As[128 * LSTR];
  __shared__ __align__(16) u16 Bs[128 * LSTR];
  __shared__ float part[128];
  const int tid = threadIdx.x;
  const int lane = tid & 63, wid = tid >> 6;
  const int wr = (wid >> 1) * 64, wc = (wid & 1) * 64;
  const int m = lane & 15, q = lane >> 4;
  const int row0 = blockIdx.x * 128, head = blockIdx.y;
  const u16* Bt = W1t + (size_t)head * 128 * 64;
  f32x4 acc[4][4] = {};
  #pragma unroll
  for (int kk = 0; kk < 64; kk += 32) {
    #pragma unroll
    for (int i = 0; i < 2; ++i) {
      int v = tid + i * 256;
      int row = v >> 2, ch = (v & 3) * 8;
      uint4 u = make_uint4(0, 0, 0, 0);
      int gr = row0 + row;
      if (gr < M) u = *(const uint4*)(aggne + (size_t)gr * 256 + head * 64 + kk + ch);
      *(uint4*)(As + row * LSTR + ch) = u;
    }
    #pragma unroll
    for (int i = 0; i < 2; ++i) {
      int v = tid + i * 256;
      int row = v >> 2, ch = (v & 3) * 8;
      uint4 u = *(const uint4*)(Bt + (size_t)row * 64 + kk + ch);
      *(uint4*)(Bs + row * LSTR + ch) = u;
    }
    __syncthreads();
    short8 af[4], bfr[4];
    #pragma unroll
    for (int t = 0; t < 4; ++t) {
      af[t]  = *(const short8*)(As + (wr + t * 16 + m) * LSTR + q * 8);
      bfr[t] = *(const short8*)(Bs + (wc + t * 16 + m) * LSTR + q * 8);
    }
    #pragma unroll
    for (int mt = 0; mt < 4; ++mt)
      #pragma unroll
      for (int nt = 0; nt < 4; ++nt)
        acc[mt][nt] = __builtin_amdgcn_mfma_f32_16x16x32_bf16(
            af[mt], bfr[nt], acc[mt][nt], 0, 0, 0);
    __syncthreads();
  }
  if (tid < 128) part[tid] = 0.f;
  // per-row weights: coalesced load + readlane broadcast
  float c_l = 0.f;
  int crow = row0 + wr + lane;
  if (crow < M) c_l = cwt[crow];
  float cvr[16];
  #pragma unroll
  for (int mt = 0; mt < 4; ++mt)
    #pragma unroll
    for (int r = 0; r < 4; ++r)
      cvr[mt * 4 + r] = rlf(c_l, mt * 16 + q * 4 + r);
  __syncthreads();
  float colacc[4] = {};
  #pragma unroll
  for (int nt = 0; nt < 4; ++nt) {
    float b = b1f[head * 128 + wc + nt * 16 + m];
    #pragma unroll
    for (int mt = 0; mt < 4; ++mt)
      #pragma unroll
      for (int r = 0; r < 4; ++r) {
        float v = acc[mt][nt][r] + b;
        v = v > 0.f ? v : (__expf(v) - 1.0f);   // ELU
        colacc[nt] = fmaf(cvr[mt * 4 + r], v, colacc[nt]);
      }
  }
  #pragma unroll
  for (int nt = 0; nt < 4; ++nt) {              // reduce over q-lanes
    colacc[nt] += __shfl_xor(colacc[nt], 16, 64);
    colacc[nt] += __shfl_xor(colacc[nt], 32, 64);
    if (q == 0) atomicAdd(&part[wc + nt * 16 + m], colacc[nt]);
  }
  __syncthreads();
  if (tid < 128) atomicAdd(&s_vec[head * 128 + tid], part[tid]);
}

// ---------------- fused layer-1 aggregation (round-3 form + readlane bcast) ----
__global__ __launch_bounds__(256) void k_fagg1(const int* __restrict__ row_off,
                                               const u16* __restrict__ srcs,
                                               const u16* __restrict__ ne_b,
                                               const float* __restrict__ as1,
                                               const float* __restrict__ ad1,
                                               u16* __restrict__ aggne) {
  int wid = threadIdx.x >> 6, lane = threadIdx.x & 63;
  int n = blockIdx.x * 4 + wid;
  if (n >= N_NODES) return;
  int start = row_off[n], end = row_off[n + 1];
  int g = lane >> 4, il = lane & 15;     // head group g, lane-in-group
  float adn_g = ad1[n * 4 + g];
  float sum = 0.f;
  for (int e0 = start; e0 < end; e0 += 16) {
    int e = e0 + il;
    if (e < end) sum += __expf(lrelu(as1[(int)srcs[e] * 4 + g] + adn_g));
  }
  #pragma unroll
  for (int off = 8; off >= 1; off >>= 1) sum += __shfl_xor(sum, off, 64);
  float inv = 1.0f / (sum + 1e-16f);
  float i_[4], d_[4];
  #pragma unroll
  for (int h = 0; h < 4; ++h) {
    i_[h] = rlf(inv, h * 16);
    d_[h] = rlf(adn_g, h * 16);
  }
  float acc[4] = {};
  for (int e0 = start; e0 < end; e0 += 64) {
    int lim = end - e0; if (lim > 64) lim = 64;
    int es = e0 + lane;
    int sreg = (int)srcs[es < end ? es : end - 1];
    float4 a = *(const float4*)(as1 + sreg * 4);
    float wreg[4];
    wreg[0] = __expf(lrelu(a.x + d_[0])) * i_[0];
    wreg[1] = __expf(lrelu(a.y + d_[1])) * i_[1];
    wreg[2] = __expf(lrelu(a.z + d_[2])) * i_[2];
    wreg[3] = __expf(lrelu(a.w + d_[3])) * i_[3];
    int j = 0;
    for (; j + 3 < lim; j += 4) {           // 4 rows in flight, SALU broadcasts
      int sa = rli(sreg, j),     sb = rli(sreg, j + 1);
      int sc = rli(sreg, j + 2), sd = rli(sreg, j + 3);
      float f0 = bf2f(ne_b[(size_t)sa * 64 + lane]);
      float f1 = bf2f(ne_b[(size_t)sb * 64 + lane]);
      float f2 = bf2f(ne_b[(size_t)sc * 64 + lane]);
      float f3 = bf2f(ne_b[(size_t)sd * 64 + lane]);
      #pragma unroll
      for (int h = 0; h < 4; ++h) {
        acc[h] = fmaf(rlf(wreg[h], j), f0, acc[h]);
        acc[h] = fmaf(rlf(wreg[h], j + 1), f1, acc[h]);
        acc[h] = fmaf(rlf(wreg[h], j + 2), f2, acc[h]);
        acc[h] = fmaf(rlf(wreg[h], j + 3), f3, acc[h]);
      }
    }
    for (; j < lim; ++j) {
      int sa = rli(sreg, j);
      float f0 = bf2f(ne_b[(size_t)sa * 64 + lane]);
      #pragma unroll
      for (int h = 0; h < 4; ++h)
        acc[h] = fmaf(rlf(wreg[h], j), f0, acc[h]);
    }
  }
  #pragma unroll
  for (int h = 0; h < 4; ++h)
    aggne[(size_t)n * 256 + h * 64 + lane] = f2bf(acc[h]);
}

// ---------------- layer-2: per-src total softmax weight c[s], no max pass ----
__global__ __launch_bounds__(256) void k_nodew(const int* __restrict__ row_off,
                                               const u16* __restrict__ srcs,
                                               const float* __restrict__ as2,
                                               const float* __restrict__ ad2,
                                               float* __restrict__ c) {
  int wid = threadIdx.x >> 6, lane = threadIdx.x & 63;
  int n = blockIdx.x * 4 + wid;
  if (n >= N_NODES) return;
  int start = row_off[n], end = row_off[n + 1];
  int deg = end - start;
  float adn = ad2[n];
  if (deg <= 64) {
    int e = start + (lane < deg ? lane : 0);
    int s = (int)srcs[e];
    float ex = (lane < deg) ? __expf(lrelu(as2[s] + adn)) : 0.f;
    float sum = ex;
    #pragma unroll
    for (int off = 32; off >= 1; off >>= 1) sum += __shfl_xor(sum, off, 64);
    float w = ex / (sum + 1e-16f);
    if (lane < deg) atomicAdd(&c[s], w);
  } else {
    float sum = 0.f;
    for (int e = start + lane; e < end; e += 64)
      sum += __expf(lrelu(as2[(int)srcs[e]] + adn));
    #pragma unroll
    for (int off = 32; off >= 1; off >>= 1) sum += __shfl_xor(sum, off, 64);
    float inv = 1.0f / (sum + 1e-16f);
    for (int e = start + lane; e < end; e += 64) {
      int s = (int)srcs[e];
      float w = __expf(lrelu(as2[s] + adn)) * inv;
      atomicAdd(&c[s], w);
    }
  }
}

// ---------------- tiny GEMM + final output (merged) ----------------
__global__ __launch_bounds__(256) void k_tinyfinal(const float* __restrict__ s_vec,
                                                   const u16* __restrict__ W2t,
                                                   const float* __restrict__ b2f,
                                                   float* __restrict__ out,
                                                   int out_size) {
  int wid = threadIdx.x >> 6, lane = threadIdx.x & 63;
  int cbase = blockIdx.x * 64 + wid * 16;
  float sv[8];
  #pragma unroll
  for (int j = 0; j < 8; ++j) sv[j] = s_vec[lane * 8 + j];
  for (int i = 0; i < 16; ++i) {
    int cc = cbase + i;
    uint4 u = *(const uint4*)(W2t + (size_t)cc * 512 + lane * 8);
    float f[8];
    unpack8(u, f);
    float p = 0.f;
    #pragma unroll
    for (int j = 0; j < 8; ++j) p = fmaf(sv[j], f[j], p);
    #pragma unroll
    for (int off = 32; off >= 1; off >>= 1) p += __shfl_xor(p, off, 64);
    if (lane == 0) {
      float val = p * (1.0f / (float)N_NODES) + b2f[cc];
      for (int o = cc; o < out_size; o += 256) out[o] = val;
    }
  }
}

// ---------------- launch ----------------
extern "C" void kernel_launch(void* const* d_in, const int* in_sizes, int n_in,
                              void* d_out, int out_size, void* d_ws, size_t ws_size,
                              hipStream_t stream) {
  (void)in_sizes; (void)n_in; (void)ws_size;
  const int* edge_index = (const int*)d_in[0];
  float* out = (float*)d_out;   // reference output dtype is float32

  char* w = (char*)d_ws;
  size_t off = 0;
  auto alloc = [&](size_t bytes) -> void* {
    void* p = w + off;
    off += (bytes + 255) & ~(size_t)255;
    return p;
  };
  u16*   ne_b    = (u16*)  alloc((size_t)N_NODES * 64 * 2);   // 6.4 MB bf16
  u16*   W1t     = (u16*)  alloc(32768 * 2);                  // [512][64]
  u16*   W2t     = (u16*)  alloc(131072 * 2);                 // [256][512]
  float* as1v    = (float*)alloc(512 * 4);
  float* ad1v    = (float*)alloc(512 * 4);
  float* b1f     = (float*)alloc(512 * 4);
  float* as2v    = (float*)alloc(256 * 4);
  float* ad2v    = (float*)alloc(256 * 4);
  float* b2f     = (float*)alloc(256 * 4);
  float* va_s    = (float*)alloc(256 * 4);
  float* va_d    = (float*)alloc(256 * 4);
  float* va2_s   = (float*)alloc(512 * 4);
  float* va2_d   = (float*)alloc(512 * 4);
  u16*   aggne   = (u16*)  alloc((size_t)N_NODES * 256 * 2);  // 25.6 MB
  float* as1     = (float*)alloc((size_t)N_NODES * 4 * 4);
  float* ad1     = (float*)alloc((size_t)N_NODES * 4 * 4);
  // ---- zeroed-every-call region (contiguous, one memset) ----
  size_t z0 = off;
  float* as2     = (float*)alloc((size_t)N_NODES * 4);   // atomic targets
  float* ad2     = (float*)alloc((size_t)N_NODES * 4);
  float* cwt     = (float*)alloc((size_t)N_NODES * 4);
  float* s_vec   = (float*)alloc(512 * 4);
  int*   deg     = (int*)  alloc((size_t)N_NODES * 4);
  size_t z1 = off;
  // -----------------------------------------------------------
  int*   row_off = (int*)  alloc((size_t)(N_NODES + 1) * 4);
  u16*   relbuf  = (u16*)  alloc((size_t)ET * 2);             // per-edge rank
  u16*   srcs    = (u16*)  alloc((size_t)ET * 2);             // node ids fit u16
  int*   btot    = (int*)  alloc(64 * 4);

  hipMemsetAsync(w + z0, 0, z1 - z0, stream);

  // prep: degree(+rank) + ne cvt (vec8) + weight transposes + params
  k_prep<<<EBLK + NEBLK8 + 640 + 9, 256, 0, stream>>>(
      edge_index, deg, relbuf, d_in[2], ne_b, d_in[3], W1t, d_in[7], W2t,
      d_in[4], d_in[5], d_in[6], d_in[8], d_in[9], d_in[10],
      as1v, ad1v, b1f, as2v, ad2v, b2f);

  // CSR partial scan + va vectors (merged), then fused add
  k_partial<<<50, 1024, 0, stream>>>(deg, row_off, btot,
                                     W1t, as1v, ad1v, va_s, va_d,
                                     W2t, as2v, ad2v, va2_s, va2_d);
  k_add<<<49, 1024, 0, stream>>>(row_off, btot, 49);

  // scatter (rank-based, no atomics) + alpha1 (merged, 16-wide reductions)
  k_scal<<<EBLK + (N_NODES + 3) / 4, 256, 0, stream>>>(
      edge_index, row_off, relbuf, srcs, ne_b, va_s, va_d, as1, ad1);

  // layer 1: fused agg over ne, then x2-free GEMM passes
  k_fagg1<<<(N_NODES + 3) / 4, 256, 0, stream>>>(row_off, srcs, ne_b, as1, ad1, aggne);
  dim3 gl1((N_NODES + 127) / 128, 4);
  k_gemm_as2<<<gl1, 256, 0, stream>>>(aggne, W1t, b1f, va2_s, va2_d, as2, ad2,
                                      N_NODES);

  // layer 2 (mean-reassociated, x2 recomputed in-register)
  k_nodew<<<(N_NODES + 3) / 4, 256, 0, stream>>>(row_off, srcs, as2, ad2, cwt);
  k_gemm_ws<<<gl1, 256, 0, stream>>>(aggne, W1t, b1f, cwt, s_vec, N_NODES);
  k_tinyfinal<<<4, 256, 0, stream>>>(s_vec, W2t, b2f, out, out_size);
}